// Round 5
// baseline (460.109 us; speedup 1.0000x reference)
//
#include <hip/hip_runtime.h>

// DynamicConv2d: B=64, C=8, H=W=256, OUT_C=8, K=3, IN_FEAT=8
// out[b,oc,h,w] = sum_{ic,kh,kw} x[b,ic,h+kh-1,w+kw-1] *
//                 ( dot(dw[b,oc,:], Wg[ic*9+kh*3+kw,:]) + bg[ic*9+kh*3+kw] )
//
// Session log (dispatch times for the conv kernel):
//   R0: RPB=8 thread-per-column, 68 VGPR, occ 25.8%        -> 90.6 us (best)
//   R2: wave-per-row + nt dwordx4 stores: 4x WRITE amplif. -> 284 us
//   R3: + plain stores, shuffle halos: VALU up, FETCH up   -> 101 us
//   R4: 8-wave blocks + gather halos: all reuse lost       -> 268 us
//   R5 (this): EXACT R0 structure, single change RPB 8->4 (acc 64->32 VGPR)
//   Lessons: (1) never nt-store sub-64B/lane on gfx950 (TCC doesn't merge);
//   (2) thread-per-column stride-1 scalar loads beat dwordx4+halo tricks here
//   (store traffic exactly 131 MB, fetch 82.6 MB — both minimal measured);
//   (3) shuffles for halo cost more VALU than the L1-hit loads they replace.

#define HC   65536   // H*W
#define WW   256
#define RPB  4       // output rows per block (was 8: acc[8][8]=64 VGPR capped
                     // occupancy at 25.8%; 4 -> acc[4][8]=32 VGPR)

// ---------------------------------------------------------------------------
// Kernel 1: materialize per-sample conv weights into d_ws with layout
//   kern[b][ic][kh][kw][oc]  (so conv reads 72 contiguous floats per (b,ic))
// ---------------------------------------------------------------------------
__global__ __launch_bounds__(576) void gen_kernels(
    const float* __restrict__ dw,   // (B, 8, 8)
    const float* __restrict__ Wg,   // (72, 8)
    const float* __restrict__ bg,   // (72,)
    float* __restrict__ kern)       // (B, 576)
{
    const int b = blockIdx.x;
    const int j = threadIdx.x;
    if (j >= 576) return;
    const int ic   = j / 72;
    const int rem  = j % 72;
    const int kh   = rem / 24;
    const int rem2 = rem % 24;
    const int kw   = rem2 / 8;
    const int oc   = rem2 % 8;
    const int o    = ic * 9 + kh * 3 + kw;   // lin output index

    const float* d = dw + b * 64 + oc * 8;
    const float* g = Wg + o * 8;
    float v = bg[o];
#pragma unroll
    for (int i = 0; i < 8; ++i) v = fmaf(d[i], g[i], v);
    kern[b * 576 + j] = v;
}

// ---------------------------------------------------------------------------
// Kernel 2: the conv. One block = one sample b x one RPB-row tile, 256
// threads = one thread per W column (stride-1 coalesced scalar loads and
// stores — empirically the minimal-traffic pattern: FETCH 82.6 MB,
// WRITE 131.0 MB at RPB=8). Each thread accumulates RPB rows x 8 oc.
// ---------------------------------------------------------------------------
__global__ __launch_bounds__(256, 8) void dyn_conv_ws(
    const float* __restrict__ x,     // (B, 8, 256, 256)
    const float* __restrict__ kern,  // (B, 576) in [ic][kh][kw][oc] layout
    float* __restrict__ out)         // (B, 8, 256, 256)
{
    const int b  = blockIdx.y;
    const int h0 = blockIdx.x * RPB;
    const int w  = threadIdx.x;

    const float* xb = x + (size_t)b * 8 * HC;
    const float* Kb = kern + b * 576;
    float*       ob = out + (size_t)b * 8 * HC;

    float acc[RPB][8];
#pragma unroll
    for (int r = 0; r < RPB; ++r)
#pragma unroll
        for (int oc = 0; oc < 8; ++oc) acc[r][oc] = 0.f;

#pragma unroll 1
    for (int ic = 0; ic < 8; ++ic) {
        // 72 wave-uniform weights for this ic -> SGPRs (measured: SGPR=112)
        float wk[72];
        const float* Kic = Kb + ic * 72;
#pragma unroll
        for (int t = 0; t < 72; ++t) wk[t] = Kic[t];

        const float* xch = xb + ic * HC;
#pragma unroll
        for (int ri = 0; ri < RPB + 2; ++ri) {
            const int row = h0 - 1 + ri;
            float xm = 0.f, xc = 0.f, xp = 0.f;
            if (row >= 0 && row < 256) {          // uniform per block
                const float* xr = xch + row * WW;
                xc = xr[w];
                xm = (w > 0)   ? xr[w - 1] : 0.f; // per-lane edge guard
                xp = (w < 255) ? xr[w + 1] : 0.f;
            }
            // input row (h0-1+ri) feeds output row ro = ri - kh
#pragma unroll
            for (int kh = 0; kh < 3; ++kh) {
                const int ro = ri - kh;
                if (ro < 0 || ro >= RPB) continue;  // compile-time pruned
                const float* wr = &wk[kh * 24];
#pragma unroll
                for (int oc = 0; oc < 8; ++oc) {
                    float a = acc[ro][oc];
                    a = fmaf(xm, wr[0 * 8 + oc], a);
                    a = fmaf(xc, wr[1 * 8 + oc], a);
                    a = fmaf(xp, wr[2 * 8 + oc], a);
                    acc[ro][oc] = a;
                }
            }
        }
    }

    const int hw0 = h0 * WW + w;
#pragma unroll
    for (int oc = 0; oc < 8; ++oc) {
        float* orow = ob + oc * HC + hw0;
#pragma unroll
        for (int r = 0; r < RPB; ++r) orow[r * WW] = acc[r][oc];
    }
}

// ---------------------------------------------------------------------------
// Fallback: fused variant (weights computed into LDS) if ws is too small.
// ---------------------------------------------------------------------------
__global__ __launch_bounds__(256) void dyn_conv_fused(
    const float* __restrict__ x,
    const float* __restrict__ dw,
    const float* __restrict__ Wg,
    const float* __restrict__ bg,
    float* __restrict__ out)
{
    __shared__ float kl[576];
    const int b  = blockIdx.y;
    const int h0 = blockIdx.x * RPB;
    const int w  = threadIdx.x;

    for (int j = threadIdx.x; j < 576; j += 256) {
        const int ic   = j / 72;
        const int rem  = j % 72;
        const int kh   = rem / 24;
        const int rem2 = rem % 24;
        const int kw   = rem2 / 8;
        const int oc   = rem2 % 8;
        const int o    = ic * 9 + kh * 3 + kw;
        const float* d = dw + b * 64 + oc * 8;
        const float* g = Wg + o * 8;
        float v = bg[o];
#pragma unroll
        for (int i = 0; i < 8; ++i) v = fmaf(d[i], g[i], v);
        kl[j] = v;
    }
    __syncthreads();

    const float* xb = x + (size_t)b * 8 * HC;
    float*       ob = out + (size_t)b * 8 * HC;

    float acc[RPB][8];
#pragma unroll
    for (int r = 0; r < RPB; ++r)
#pragma unroll
        for (int oc = 0; oc < 8; ++oc) acc[r][oc] = 0.f;

#pragma unroll 1
    for (int ic = 0; ic < 8; ++ic) {
        const float* xch = xb + ic * HC;
#pragma unroll
        for (int ri = 0; ri < RPB + 2; ++ri) {
            const int row = h0 - 1 + ri;
            float xm = 0.f, xc = 0.f, xp = 0.f;
            if (row >= 0 && row < 256) {
                const float* xr = xch + row * WW;
                xc = xr[w];
                xm = (w > 0)   ? xr[w - 1] : 0.f;
                xp = (w < 255) ? xr[w + 1] : 0.f;
            }
#pragma unroll
            for (int kh = 0; kh < 3; ++kh) {
                const int ro = ri - kh;
                if (ro < 0 || ro >= RPB) continue;
                const float* wr = &kl[0] + ic * 72 + kh * 24;
#pragma unroll
                for (int oc = 0; oc < 8; ++oc) {
                    float a = acc[ro][oc];
                    a = fmaf(xm, wr[0 * 8 + oc], a);
                    a = fmaf(xc, wr[1 * 8 + oc], a);
                    a = fmaf(xp, wr[2 * 8 + oc], a);
                    acc[ro][oc] = a;
                }
            }
        }
    }

    const int hw0 = h0 * WW + w;
#pragma unroll
    for (int oc = 0; oc < 8; ++oc) {
        float* orow = ob + oc * HC + hw0;
#pragma unroll
        for (int r = 0; r < RPB; ++r) orow[r * WW] = acc[r][oc];
    }
}

extern "C" void kernel_launch(void* const* d_in, const int* in_sizes, int n_in,
                              void* d_out, int out_size, void* d_ws, size_t ws_size,
                              hipStream_t stream) {
    const float* x  = (const float*)d_in[0];  // (64,8,256,256)
    const float* dw = (const float*)d_in[1];  // (64,8,8)
    const float* Wg = (const float*)d_in[2];  // (72,8)
    const float* bg = (const float*)d_in[3];  // (72,)
    float* out = (float*)d_out;

    const dim3 grid(256 / RPB, 64);   // 64 row-tiles x 64 samples
    const dim3 block(256);

    if (ws_size >= (size_t)(64 * 576 * sizeof(float))) {
        float* kern = (float*)d_ws;
        gen_kernels<<<dim3(64), dim3(576), 0, stream>>>(dw, Wg, bg, kern);
        dyn_conv_ws<<<grid, block, 0, stream>>>(x, kern, out);
    } else {
        dyn_conv_fused<<<grid, block, 0, stream>>>(x, dw, Wg, bg, out);
    }
}

// Round 6
// 244.911 us; speedup vs baseline: 1.8787x; 1.8787x over previous
//
#include <hip/hip_runtime.h>

// DynamicConv2d: B=64, C=8, H=W=256, OUT_C=8, K=3, IN_FEAT=8
// out[b,oc,h,w] = sum_{ic,kh,kw} x[b,ic,h+kh-1,w+kw-1] *
//                 ( dot(dw[b,oc,:], Wg[ic*9+kh*3+kw,:]) + bg[ic*9+kh*3+kw] )
//
// Session log (conv-dispatch times):
//   R0: RPB=8, __launch_bounds__(256), 68 VGPR, occ 25.8%   -> 90.6 us
//   R2-R5: various tilings, ALL with __launch_bounds__(..,8) -> 101-300 us
//   DIAGNOSIS (R5): the min-waves=8 arg capped the allocator at 32 VGPRs
//   (= acc alone) -> inner-loop spilled to scratch -> WRITE_SIZE 686 MB
//   (5.2x output!), FETCH 329 MB. Spill traffic, not cache behavior,
//   caused every "write amplification" seen in R2/R4/R5.
//   R6 (this): R0 structure, RPB 8->4 (acc 64->32 VGPR), NO min-waves
//   forcing. Natural alloc ~50 VGPR <= 64 -> full occupancy w/o spills.
//   Rules learned: (1) __launch_bounds__ 2nd arg is a VGPR budget —
//   over-asking converts registers into scratch traffic; (2) plain
//   stride-1 scalar wave-stores write exactly output-size (131 MB);
//   (3) shuffle halos cost more than L1-hit neighbor loads.

#define HC   65536   // H*W
#define WW   256
#define RPB  4       // output rows per block (acc[4][8]=32 VGPR + temps ~50)

// ---------------------------------------------------------------------------
// Kernel 1: materialize per-sample conv weights into d_ws with layout
//   kern[b][ic][kh][kw][oc]  (so conv reads 72 contiguous floats per (b,ic))
// ---------------------------------------------------------------------------
__global__ __launch_bounds__(576) void gen_kernels(
    const float* __restrict__ dw,   // (B, 8, 8)
    const float* __restrict__ Wg,   // (72, 8)
    const float* __restrict__ bg,   // (72,)
    float* __restrict__ kern)       // (B, 576)
{
    const int b = blockIdx.x;
    const int j = threadIdx.x;
    if (j >= 576) return;
    const int ic   = j / 72;
    const int rem  = j % 72;
    const int kh   = rem / 24;
    const int rem2 = rem % 24;
    const int kw   = rem2 / 8;
    const int oc   = rem2 % 8;
    const int o    = ic * 9 + kh * 3 + kw;   // lin output index

    const float* d = dw + b * 64 + oc * 8;
    const float* g = Wg + o * 8;
    float v = bg[o];
#pragma unroll
    for (int i = 0; i < 8; ++i) v = fmaf(d[i], g[i], v);
    kern[b * 576 + j] = v;
}

// ---------------------------------------------------------------------------
// Kernel 2: the conv. One block = one sample b x one RPB-row tile, 256
// threads = one thread per W column (stride-1 coalesced scalar loads and
// stores — the measured minimal-traffic pattern). Each thread accumulates
// RPB rows x 8 oc. NO min-waves in __launch_bounds__: let the allocator
// use ~50 VGPRs; <=64 VGPR already permits 32 waves/CU.
// ---------------------------------------------------------------------------
__global__ __launch_bounds__(256) void dyn_conv_ws(
    const float* __restrict__ x,     // (B, 8, 256, 256)
    const float* __restrict__ kern,  // (B, 576) in [ic][kh][kw][oc] layout
    float* __restrict__ out)         // (B, 8, 256, 256)
{
    const int b  = blockIdx.y;
    const int h0 = blockIdx.x * RPB;
    const int w  = threadIdx.x;

    const float* xb = x + (size_t)b * 8 * HC;
    const float* Kb = kern + b * 576;
    float*       ob = out + (size_t)b * 8 * HC;

    float acc[RPB][8];
#pragma unroll
    for (int r = 0; r < RPB; ++r)
#pragma unroll
        for (int oc = 0; oc < 8; ++oc) acc[r][oc] = 0.f;

#pragma unroll 1
    for (int ic = 0; ic < 8; ++ic) {
        // 72 wave-uniform weights for this ic -> SGPRs
        float wk[72];
        const float* Kic = Kb + ic * 72;
#pragma unroll
        for (int t = 0; t < 72; ++t) wk[t] = Kic[t];

        const float* xch = xb + ic * HC;
#pragma unroll
        for (int ri = 0; ri < RPB + 2; ++ri) {
            const int row = h0 - 1 + ri;
            float xm = 0.f, xc = 0.f, xp = 0.f;
            if (row >= 0 && row < 256) {          // uniform per block
                const float* xr = xch + row * WW;
                xc = xr[w];
                xm = (w > 0)   ? xr[w - 1] : 0.f; // per-lane edge guard
                xp = (w < 255) ? xr[w + 1] : 0.f;
            }
            // input row (h0-1+ri) feeds output row ro = ri - kh
#pragma unroll
            for (int kh = 0; kh < 3; ++kh) {
                const int ro = ri - kh;
                if (ro < 0 || ro >= RPB) continue;  // compile-time pruned
                const float* wr = &wk[kh * 24];
#pragma unroll
                for (int oc = 0; oc < 8; ++oc) {
                    float a = acc[ro][oc];
                    a = fmaf(xm, wr[0 * 8 + oc], a);
                    a = fmaf(xc, wr[1 * 8 + oc], a);
                    a = fmaf(xp, wr[2 * 8 + oc], a);
                    acc[ro][oc] = a;
                }
            }
        }
    }

    const int hw0 = h0 * WW + w;
#pragma unroll
    for (int oc = 0; oc < 8; ++oc) {
        float* orow = ob + oc * HC + hw0;
#pragma unroll
        for (int r = 0; r < RPB; ++r) orow[r * WW] = acc[r][oc];
    }
}

// ---------------------------------------------------------------------------
// Fallback: fused variant (weights computed into LDS) if ws is too small.
// ---------------------------------------------------------------------------
__global__ __launch_bounds__(256) void dyn_conv_fused(
    const float* __restrict__ x,
    const float* __restrict__ dw,
    const float* __restrict__ Wg,
    const float* __restrict__ bg,
    float* __restrict__ out)
{
    __shared__ float kl[576];
    const int b  = blockIdx.y;
    const int h0 = blockIdx.x * RPB;
    const int w  = threadIdx.x;

    for (int j = threadIdx.x; j < 576; j += 256) {
        const int ic   = j / 72;
        const int rem  = j % 72;
        const int kh   = rem / 24;
        const int rem2 = rem % 24;
        const int kw   = rem2 / 8;
        const int oc   = rem2 % 8;
        const int o    = ic * 9 + kh * 3 + kw;
        const float* d = dw + b * 64 + oc * 8;
        const float* g = Wg + o * 8;
        float v = bg[o];
#pragma unroll
        for (int i = 0; i < 8; ++i) v = fmaf(d[i], g[i], v);
        kl[j] = v;
    }
    __syncthreads();

    const float* xb = x + (size_t)b * 8 * HC;
    float*       ob = out + (size_t)b * 8 * HC;

    float acc[RPB][8];
#pragma unroll
    for (int r = 0; r < RPB; ++r)
#pragma unroll
        for (int oc = 0; oc < 8; ++oc) acc[r][oc] = 0.f;

#pragma unroll 1
    for (int ic = 0; ic < 8; ++ic) {
        const float* xch = xb + ic * HC;
#pragma unroll
        for (int ri = 0; ri < RPB + 2; ++ri) {
            const int row = h0 - 1 + ri;
            float xm = 0.f, xc = 0.f, xp = 0.f;
            if (row >= 0 && row < 256) {
                const float* xr = xch + row * WW;
                xc = xr[w];
                xm = (w > 0)   ? xr[w - 1] : 0.f;
                xp = (w < 255) ? xr[w + 1] : 0.f;
            }
#pragma unroll
            for (int kh = 0; kh < 3; ++kh) {
                const int ro = ri - kh;
                if (ro < 0 || ro >= RPB) continue;
                const float* wr = &kl[0] + ic * 72 + kh * 24;
#pragma unroll
                for (int oc = 0; oc < 8; ++oc) {
                    float a = acc[ro][oc];
                    a = fmaf(xm, wr[0 * 8 + oc], a);
                    a = fmaf(xc, wr[1 * 8 + oc], a);
                    a = fmaf(xp, wr[2 * 8 + oc], a);
                    acc[ro][oc] = a;
                }
            }
        }
    }

    const int hw0 = h0 * WW + w;
#pragma unroll
    for (int oc = 0; oc < 8; ++oc) {
        float* orow = ob + oc * HC + hw0;
#pragma unroll
        for (int r = 0; r < RPB; ++r) orow[r * WW] = acc[r][oc];
    }
}

extern "C" void kernel_launch(void* const* d_in, const int* in_sizes, int n_in,
                              void* d_out, int out_size, void* d_ws, size_t ws_size,
                              hipStream_t stream) {
    const float* x  = (const float*)d_in[0];  // (64,8,256,256)
    const float* dw = (const float*)d_in[1];  // (64,8,8)
    const float* Wg = (const float*)d_in[2];  // (72,8)
    const float* bg = (const float*)d_in[3];  // (72,)
    float* out = (float*)d_out;

    const dim3 grid(256 / RPB, 64);   // 64 row-tiles x 64 samples
    const dim3 block(256);

    if (ws_size >= (size_t)(64 * 576 * sizeof(float))) {
        float* kern = (float*)d_ws;
        gen_kernels<<<dim3(64), dim3(576), 0, stream>>>(dw, Wg, bg, kern);
        dyn_conv_ws<<<grid, block, 0, stream>>>(x, kern, out);
    } else {
        dyn_conv_fused<<<grid, block, 0, stream>>>(x, dw, Wg, bg, out);
    }
}